// Round 7
// baseline (471.101 us; speedup 1.0000x reference)
//
#include <hip/hip_runtime.h>

// VanillaVectorQuantizer: N=131072 positions (B=32,H=64,W=64), D=64, K=512.
// enc layout [B, D, H, W]: element (b,d,p) at b*D*HW + d*HW + p, p=h*64+w.
//
// Numerics are an EXACT emulation of the numpy fp32 reference chain
// (verified bitwise in rounds 2-6, absmax == 0):
//   - M_k: ascending-d fp32 FMA chain (== BLAS sgemm microkernel)
//   - sq_x: numpy pairwise_sum(n=64): 8 stride-8 accumulators of pre-rounded
//     squares (mul then add, NO fma), combine ((r0+r1)+(r2+r3))+((r4+r5)+(r6+r7))
//   - sq_e: sequential d-sum of pre-rounded squares (NO fma)
//   - dist: fl(fl(sq_x - fl(2*M)) + sq_e), contraction off
//   - strict '<' ascending k == np.argmin first-index tie-break
// DO NOT alter any of these chains.
//
// Perf history:
//   r2/r5 (202us, real per-SIMD VALU ~30%): cb via s_load_dwordx16. One
//     K-tile = 4KB of cb = 1024 SGPRs -> prefetch depth ~2 loads in a
//     112-SGPR file -> lgkmcnt stall every ~64 FMAs; 2 waves/SIMD
//     (grid-limited) can't cover L2 latency. SMEM path is the bottleneck.
//   r3 (477us): asm-pinned x -> scratch spill. r4 (480us): tid-derived kbase
//     -> per-lane SCALAR-WIDTH cb loads, 1024 VMEM instr/tile, issue-bound.
//   r6 (199us): x moved to LDS; confirmed x was not the cost.
// This round: cb loads forced onto the VMEM pipe as global_load_dwordx4 at a
// value-uniform address (opaque VGPR zero added to the base pointer so LLVM
// divergence analysis can't route it to SMEM). 256 VMEM/tile, deep vmcnt
// pipelining from the 256-VGPR budget; FMA(VALU) + x(LDS) + cb(VMEM) on
// three pipes. VALU floor 60us; target 75-105us.

#pragma clang fp contract(off)

#define VQ_D 64
#define VQ_K 512
#define VQ_HW 4096
#define VQ_N 131072
#define XS_STRIDE 68  // 64 + 4 pad; rows 272B (16B-aligned for b128 reads)

__global__ void vq_sqe_kernel(const float* __restrict__ cb,
                              float* __restrict__ sqe) {
    const int k = threadIdx.x;  // 512 threads, one block
    float s = cb[k] * cb[k];    // d = 0 (square rounded, then added: no fma)
    for (int d = 1; d < VQ_D; ++d) {
        const float v = cb[d * VQ_K + k];
        const float sq = v * v;  // contract(off): rounds the square
        s = s + sq;              // then rounds the add (numpy axis-0 reduce)
    }
    sqe[k] = s;
}

__global__ __launch_bounds__(256, 2) void vq_main_kernel(
    const float* __restrict__ enc, const float* __restrict__ cb,
    const float* __restrict__ sqe, float* __restrict__ out) {
    __shared__ float xs[256 * XS_STRIDE];  // 69632 B -> 2 blocks/CU

    const int tid = threadIdx.x;
    const int pos0 = blockIdx.x * 256;     // grid divides N exactly
    const int b = pos0 >> 12;              // block lies within one b (256|4096)
    const int r0 = pos0 & (VQ_HW - 1);
    const float* ebase = enc + (size_t)b * (VQ_D * VQ_HW) + r0;

    // Stage this block's 256 positions into LDS, xs[p][d].
#pragma unroll 8
    for (int d = 0; d < VQ_D; ++d)
        xs[tid * XS_STRIDE + d] = ebase[(size_t)d * VQ_HW + tid];
    __syncthreads();

    const float* xp = &xs[tid * XS_STRIDE];

    // sq_x: exact emulation of numpy pairwise_sum over fl(x*x), n=64.
    float pr[8];
#pragma unroll
    for (int j = 0; j < 8; ++j) pr[j] = xp[j] * xp[j];
#pragma unroll
    for (int i = 8; i < VQ_D; i += 8) {
#pragma unroll
        for (int j = 0; j < 8; ++j) {
            const float sq = xp[i + j] * xp[i + j];  // rounded square
            pr[j] = pr[j] + sq;                      // rounded add
        }
    }
    const float sqx = ((pr[0] + pr[1]) + (pr[2] + pr[3])) +
                      ((pr[4] + pr[5]) + (pr[6] + pr[7]));

    // Opaque zero: LLVM can't prove cbo uniform -> cb loads go to the VMEM
    // pipe (global_load_dwordx4, same addr all lanes = 1 coalesced request)
    // instead of the SGPR-starved SMEM path. Value is 0: indexing unchanged.
    int vzero;
    asm("v_mov_b32 %0, 0" : "=v"(vzero));
    const float* cbo = cb + vzero;

    float best = 3.402823466e38f;
    int bestk = 0;

    for (int kt = 0; kt < VQ_K; kt += 16) {
        float acc[16];
#pragma unroll
        for (int j = 0; j < 16; ++j) acc[j] = 0.f;
#pragma unroll
        for (int d0 = 0; d0 < VQ_D; d0 += 4) {
            // 16 float4 VMEM loads (4 d-rows x 16 k's) — deep vmcnt pipeline.
            float4 c[4][4];
#pragma unroll
            for (int dd = 0; dd < 4; ++dd) {
#pragma unroll
                for (int q = 0; q < 4; ++q)
                    c[dd][q] = *reinterpret_cast<const float4*>(
                        &cbo[(d0 + dd) * VQ_K + kt + 4 * q]);
            }
            // One ds_read_b128 of this thread's x row feeds 64 FMAs.
            const float4 xv = *reinterpret_cast<const float4*>(&xp[d0]);
            const float xa[4] = {xv.x, xv.y, xv.z, xv.w};
#pragma unroll
            for (int dd = 0; dd < 4; ++dd) {
                const float* cf = reinterpret_cast<const float*>(&c[dd][0]);
#pragma unroll
                for (int j = 0; j < 16; ++j)  // ascending-d FMA chain == sgemm
                    acc[j] = fmaf(xa[dd], cf[j], acc[j]);
            }
        }
#pragma unroll
        for (int j = 0; j < 16; ++j) {
            const float m2 = 2.0f * acc[j];        // exact (power of 2)
            const float tmp = sqx - m2;            // rounds: fl(sq_x - 2M)
            const float dist = tmp + sqe[kt + j];  // rounds: + sq_e
            if (dist < best) {  // strict '<': first (lowest) index on ties
                best = dist;
                bestk = kt + j;
            }
        }
    }

    // Gather winning codebook column, store strided (coalesced across lanes).
    float* op = out + (size_t)b * (VQ_D * VQ_HW) + r0 + tid;
#pragma unroll 8
    for (int d = 0; d < VQ_D; ++d)
        op[(size_t)d * VQ_HW] = cb[d * VQ_K + bestk];
}

extern "C" void kernel_launch(void* const* d_in, const int* in_sizes, int n_in,
                              void* d_out, int out_size, void* d_ws, size_t ws_size,
                              hipStream_t stream) {
    const float* enc = (const float*)d_in[0];  // [32,64,64,64]
    const float* cb  = (const float*)d_in[1];  // [64,512]
    float* out = (float*)d_out;
    float* sqe = (float*)d_ws;  // 512 floats

    vq_sqe_kernel<<<1, VQ_K, 0, stream>>>(cb, sqe);
    vq_main_kernel<<<VQ_N / 256, 256, 0, stream>>>(enc, cb, sqe, out);
}

// Round 8
// 202.922 us; speedup vs baseline: 2.3216x; 2.3216x over previous
//
#include <hip/hip_runtime.h>

// VanillaVectorQuantizer: N=131072 positions (B=32,H=64,W=64), D=64, K=512.
// enc layout [B, D, H, W]: element (b,d,p) at b*D*HW + d*HW + p, p=h*64+w.
//
// Numerics are an EXACT emulation of the numpy fp32 reference chain
// (verified bitwise in rounds 2-7, absmax == 0):
//   - M_k: ascending-d fp32 FMA chain (== BLAS sgemm microkernel)
//   - sq_x: numpy pairwise_sum(n=64): 8 stride-8 accumulators of pre-rounded
//     squares (mul then add, NO fma), combine ((r0+r1)+(r2+r3))+((r4+r5)+(r6+r7))
//   - sq_e: sequential d-sum of pre-rounded squares (NO fma)
//   - dist: fl(fl(sq_x - fl(2*M)) + sq_e), contraction off
//   - strict '<' ascending k == np.argmin first-index tie-break
// DO NOT alter any of these chains. (x through LDS is bitwise-exact.)
//
// Perf history:
//   r2/r5/r6 (~200us): cb via s_load_dwordx16 (SMEM) — correct transport,
//     but only 2 waves/SIMD (grid-limited) -> recurring lgkmcnt stalls on
//     L2-latency scalar loads, real VALU issue ~27% (floor is 54.6us).
//   r3 (477us): asm-pin -> scratch spill. r4 (480us): tid-derived kbase ->
//     divergence analysis demoted cb to per-lane VMEM. r7 (471us): opaque-
//     VGPR cb base -> same per-lane VMEM cost, falsified VMEM transport.
// This round: occupancy 2->4 waves/SIMD via 4-way K-split INSIDE a
// 1024-thread block. split = tid>>8 is wave-uniform and passed through
// __builtin_amdgcn_readfirstlane -> lands in an SGPR, provably uniform ->
// cb/sqe stay on the scalar path (fixes r4's mistake). x staged once in LDS;
// LDS combine with ascending-split strict '<' preserves np.argmin order;
// epilogue stores 16 d-planes per split. 1024-thread blocks force a <=128
// VGPR budget -> 16 waves/CU resident.

#pragma clang fp contract(off)

#define VQ_D 64
#define VQ_K 512
#define VQ_HW 4096
#define VQ_N 131072
#define XS_STRIDE 68  // 64 + 4 pad; rows 272B (16B-aligned for b128 reads)

__global__ void vq_sqe_kernel(const float* __restrict__ cb,
                              float* __restrict__ sqe) {
    const int k = threadIdx.x;  // 512 threads, one block
    float s = cb[k] * cb[k];    // d = 0 (square rounded, then added: no fma)
    for (int d = 1; d < VQ_D; ++d) {
        const float v = cb[d * VQ_K + k];
        const float sq = v * v;  // contract(off): rounds the square
        s = s + sq;              // then rounds the add (numpy axis-0 reduce)
    }
    sqe[k] = s;
}

__global__ __launch_bounds__(1024) void vq_main_kernel(
    const float* __restrict__ enc, const float* __restrict__ cb,
    const float* __restrict__ sqe, float* __restrict__ out) {
    __shared__ float xs[256 * XS_STRIDE];  // 69632 B
    __shared__ float sbest[1024];          //  4096 B
    __shared__ int sbk[1024];              //  4096 B

    const int tid = threadIdx.x;
    const int p = tid & 255;               // position within block
    const int pos0 = blockIdx.x * 256;     // grid divides N exactly
    const int b = pos0 >> 12;              // block lies within one b (256|4096)
    const int r0 = pos0 & (VQ_HW - 1);
    const float* ebase = enc + (size_t)b * (VQ_D * VQ_HW) + r0;

    // Stage this block's 256 positions into LDS, xs[p][d]; 16 elems/thread.
    {
        const int dbase = (tid >> 8) << 4;
#pragma unroll
        for (int i = 0; i < 16; ++i) {
            const int d = dbase + i;
            xs[p * XS_STRIDE + d] = ebase[(size_t)d * VQ_HW + p];
        }
    }
    __syncthreads();

    const float* xp = &xs[p * XS_STRIDE];

    // sq_x: exact emulation of numpy pairwise_sum over fl(x*x), n=64.
    float pr[8];
#pragma unroll
    for (int j = 0; j < 8; ++j) pr[j] = xp[j] * xp[j];
#pragma unroll
    for (int i = 8; i < VQ_D; i += 8) {
#pragma unroll
        for (int j = 0; j < 8; ++j) {
            const float sq = xp[i + j] * xp[i + j];  // rounded square
            pr[j] = pr[j] + sq;                      // rounded add
        }
    }
    const float sqx = ((pr[0] + pr[1]) + (pr[2] + pr[3])) +
                      ((pr[4] + pr[5]) + (pr[6] + pr[7]));

    // K-split: waves of tid>>8==s scan k in [128s, 128s+128).
    // readfirstlane puts kbase in an SGPR -> provably uniform -> cb/sqe
    // stay on the scalar-load path (r4's demotion avoided).
    const int kbase = __builtin_amdgcn_readfirstlane((tid >> 8) << 7);

    float best = 3.402823466e38f;
    int bestk = 0;

    for (int kt = kbase; kt < kbase + 128; kt += 16) {
        float acc[16];
#pragma unroll
        for (int j = 0; j < 16; ++j) acc[j] = 0.f;
#pragma unroll
        for (int d0 = 0; d0 < VQ_D; d0 += 4) {
            // One ds_read_b128 of this thread's x row feeds 64 FMAs.
            const float4 xv = *reinterpret_cast<const float4*>(&xp[d0]);
            const float xa[4] = {xv.x, xv.y, xv.z, xv.w};
#pragma unroll
            for (int dd = 0; dd < 4; ++dd) {
#pragma unroll
                for (int j = 0; j < 16; ++j)  // ascending-d FMA chain == sgemm
                    acc[j] = fmaf(xa[dd], cb[(d0 + dd) * VQ_K + kt + j], acc[j]);
            }
        }
#pragma unroll
        for (int j = 0; j < 16; ++j) {
            const float m2 = 2.0f * acc[j];        // exact (power of 2)
            const float tmp = sqx - m2;            // rounds: fl(sq_x - 2M)
            const float dist = tmp + sqe[kt + j];  // rounds: + sq_e
            if (dist < best) {  // strict '<': first (lowest) index on ties
                best = dist;
                bestk = kt + j;
            }
        }
    }

    // Combine the 4 k-splits (disjoint ascending ranges; ascending-split scan
    // with strict '<' == global np.argmin first-index semantics).
    sbest[tid] = best;
    sbk[tid] = bestk;
    __syncthreads();
    if (tid < 256) {
        float bb = sbest[p];
        int bk = sbk[p];
#pragma unroll
        for (int s = 1; s < 4; ++s) {
            const float ob = sbest[(s << 8) + p];
            if (ob < bb) {
                bb = ob;
                bk = sbk[(s << 8) + p];
            }
        }
        sbk[p] = bk;  // publish final index
    }
    __syncthreads();
    const int kfin = sbk[p];

    // Gather winning codebook column; each split stores 16 of the 64
    // d-planes (stores 256B-contiguous per wave: 64 consecutive positions).
    float* op = out + (size_t)b * (VQ_D * VQ_HW) + r0 + p;
    const int dbase = (tid >> 8) << 4;
#pragma unroll
    for (int sd = 0; sd < 16; ++sd) {
        const int d = dbase + sd;
        op[(size_t)d * VQ_HW] = cb[d * VQ_K + kfin];
    }
}

extern "C" void kernel_launch(void* const* d_in, const int* in_sizes, int n_in,
                              void* d_out, int out_size, void* d_ws, size_t ws_size,
                              hipStream_t stream) {
    const float* enc = (const float*)d_in[0];  // [32,64,64,64]
    const float* cb  = (const float*)d_in[1];  // [64,512]
    float* out = (float*)d_out;
    float* sqe = (float*)d_ws;  // 512 floats

    vq_sqe_kernel<<<1, VQ_K, 0, stream>>>(cb, sqe);
    vq_main_kernel<<<VQ_N / 256, 1024, 0, stream>>>(enc, cb, sqe, out);
}